// Round 7
// baseline (195.685 us; speedup 1.0000x reference)
//
#include <hip/hip_runtime.h>

// yoloLoss on MI355X — memory-bound streaming reduction.
// pred/target: (4096,14,14,30) fp32. Output: scalar fp32.
//
// R7: 3-way discriminator. In the nt regime, three schedules (R4/R5/R6)
// all tie at main ~55-58us = 3.4 TB/s read. Harness dispatches show
// writes reach 6.7 TB/s (fill) but no read stream exceeds ~3.4 (copy's
// read side = 3.3). m146 proves plain-load reads can do 4.9 TB/s in a
// clean state. Suspects: (1) nt flag caps reads (uncached ~900cy latency
// x per-CU outstanding limit => ~3 TB/s chip, Little's law), or (2) the
// poisoned-dirty state caps reads regardless. Test: pred -> PLAIN loads
// (can hit/allocate L2/L3, halves potential storm), tgt -> nt (keeps
// half the storm suppressed). Outcomes: nt-cap => ~178-184 total;
// storm-dominant => ~196-200; state-cap => ~189-191 (then ROOFLINE).
// Structure = R5 (best measured, 189.1): all loads issued up front,
// sched_barrier pin, pred->LDS->regs, tgt->LDS->regs, compute, reduce.
// Numerics identical: same tiles, lane<->cell map, reduce tree.

#define FEAT 30               // B*5 + C = 2*5 + 20
#define CELLS 802816          // 4096*14*14
#define TPB 256               // threads per block
#define CPB 256               // cells per block (1 cell/thread)
#define NBLOCKS (CELLS / CPB) // 3136 exactly
#define F4_PER_ARRAY (CPB * FEAT / 4) // 1920 float4 per array per tile

typedef float f32x4 __attribute__((ext_vector_type(4)));

__device__ __forceinline__ float iou_f(float x1, float y1, float w1, float h1,
                                       float x2, float y2, float w2, float h2) {
    float b1x1 = x1 - 0.5f * w1, b1x2 = x1 + 0.5f * w1;
    float b1y1 = y1 - 0.5f * h1, b1y2 = y1 + 0.5f * h1;
    float b2x1 = x2 - 0.5f * w2, b2x2 = x2 + 0.5f * w2;
    float b2y1 = y2 - 0.5f * h2, b2y2 = y2 + 0.5f * h2;
    float iw = fmaxf(fminf(b1x2, b2x2) - fmaxf(b1x1, b2x1), 0.0f);
    float ih = fmaxf(fminf(b1y2, b2y2) - fmaxf(b1y1, b2y1), 0.0f);
    float inter = iw * ih;
    float a1 = (b1x2 - b1x1) * (b1y2 - b1y1);
    float a2 = (b2x2 - b2x1) * (b2y2 - b2y1);
    return inter / (a1 + a2 - inter + 1e-6f);
}

__global__ __launch_bounds__(TPB, 4) void yolo_main_kernel(
        const float* __restrict__ pred, const float* __restrict__ tgt,
        float* __restrict__ partials) {
    // 30720 B tile buffer, written twice per block (pred then tgt).
    __shared__ float sb[CPB * FEAT];
    __shared__ float wave_sum[TPB / 64];

    const int tid = threadIdx.x;
    const long long base = (long long)blockIdx.x * (CPB * FEAT);
    const bool tail = tid < (F4_PER_ARRAY - 7 * TPB); // 128 float4 tail

    const f32x4* gp = (const f32x4*)(pred + base);
    const f32x4* gt = (const f32x4*)(tgt + base);
    f32x4* l = (f32x4*)sb;

    // ---- Issue ALL loads up front ----
    // pred: PLAIN loads (allocate/hit L2+L3). tgt: nt (no-allocate).
    f32x4 pr[8], tr[8];
#pragma unroll
    for (int i = 0; i < 7; ++i)
        pr[i] = gp[tid + i * TPB];
    if (tail) pr[7] = gp[tid + 7 * TPB];
#pragma unroll
    for (int i = 0; i < 7; ++i)
        tr[i] = __builtin_nontemporal_load(&gt[tid + i * TPB]);
    if (tail) tr[7] = __builtin_nontemporal_load(&gt[tid + 7 * TPB]);
    // Pin issue order: scheduler must not sink the tgt loads below the
    // pred LDS writes / barrier (that would re-serialize the two latencies).
    __builtin_amdgcn_sched_barrier(0);

    // ---- Phase 1: pred -> LDS (counted vmcnt: tgt loads stay in flight) ----
#pragma unroll
    for (int i = 0; i < 7; ++i) l[tid + i * TPB] = pr[i];
    if (tail) l[tid + 7 * TPB] = pr[7];
    __syncthreads();

    float p[FEAT];
    {
        const float2* pc = (const float2*)(sb + tid * FEAT); // 8B-aligned
#pragma unroll
        for (int i = 0; i < FEAT / 2; ++i) {
            float2 v = pc[i];
            p[2 * i] = v.x;
            p[2 * i + 1] = v.y;
        }
    }
    __syncthreads(); // all pred reads done before buffer overwrite

    // ---- Phase 2: tgt -> LDS (latency already hidden under phase 1) ----
#pragma unroll
    for (int i = 0; i < 7; ++i) l[tid + i * TPB] = tr[i];
    if (tail) l[tid + 7 * TPB] = tr[7];
    __syncthreads();

    const float2* tc = (const float2*)(sb + tid * FEAT);
    float t[10];
#pragma unroll
    for (int i = 0; i < 5; ++i) { // box region: t[0..9]
        float2 v = tc[i];
        t[2 * i] = v.x;
        t[2 * i + 1] = v.y;
    }

    // --- per-cell YOLO loss (mirrors the JAX reference exactly) ---
    const bool obj0 = t[4] > 0.0f;   // box0 conf target
    const bool obj1 = t[9] > 0.0f;   // box1 conf target
    const float mf = obj0 ? 1.0f : 0.0f; // has_obj = obj_mask[...,0]

    float d0 = p[4] - t[4];
    float d1 = p[9] - t[9];
    float noobj = (obj0 ? 0.0f : d0 * d0) + (obj1 ? 0.0f : d1 * d1);

    float iou0 = iou_f(p[0], p[1], p[2], p[3], t[0], t[1], t[2], t[3]);
    float iou1 = iou_f(p[5], p[6], p[7], p[8], t[5], t[6], t[7], t[8]);
    const bool sel1 = iou1 > iou0;

    float pbx = sel1 ? p[5] : p[0];
    float pby = sel1 ? p[6] : p[1];
    float pbw = sel1 ? p[7] : p[2];
    float pbh = sel1 ? p[8] : p[3];
    float pbc = sel1 ? p[9] : p[4];
    float tbx = sel1 ? t[5] : t[0];
    float tby = sel1 ? t[6] : t[1];
    float tbw = sel1 ? t[7] : t[2];
    float tbh = sel1 ? t[8] : t[3];
    float tbc = sel1 ? t[9] : t[4];

    float dx = pbx - tbx, dy = pby - tby;
    float xy = dx * dx + dy * dy;

    float pw = sqrtf(fabsf(pbw) + 1e-6f);
    float ph = sqrtf(fabsf(pbh) + 1e-6f);
    float tw = sqrtf(obj0 ? tbw : 1.0f); // t_wh_safe: avoids NaN when !obj
    float th = sqrtf(obj0 ? tbh : 1.0f);
    float dw = pw - tw, dh = ph - th;
    float wh = dw * dw + dh * dh;

    float dc = pbc - tbc;
    float obj_l = dc * dc;

    // nonbest conf: LAMBDA_NOOBJ applied here AND again in total (ref does both)
    float nonbest = (p[4] + p[9]) - pbc;
    noobj += 0.5f * mf * nonbest * nonbest;

    // class loss: stream t[10..29] straight from LDS, accumulate
    float cls = 0.0f;
#pragma unroll
    for (int i = 5; i < FEAT / 2; ++i) {
        float2 v = tc[i];
        float da = p[2 * i] - v.x;
        float db = p[2 * i + 1] - v.y;
        cls += da * da + db * db;
    }

    float cell = 5.0f * mf * (xy + wh) + mf * obj_l + 0.5f * noobj + mf * cls;

    // --- block reduction: wave shuffle then LDS across 4 waves ---
    float v = cell;
#pragma unroll
    for (int off = 32; off > 0; off >>= 1) v += __shfl_down(v, off, 64);
    if ((tid & 63) == 0) wave_sum[tid >> 6] = v;
    __syncthreads();
    if (tid == 0)
        partials[blockIdx.x] = wave_sum[0] + wave_sum[1] + wave_sum[2] + wave_sum[3];
}

__global__ __launch_bounds__(TPB) void yolo_reduce_kernel(
        const float* __restrict__ partials, float* __restrict__ out) {
    __shared__ float wave_sum[TPB / 64];
    const int tid = threadIdx.x;
    float v = 0.0f;
    for (int i = tid; i < NBLOCKS; i += TPB) v += partials[i];
#pragma unroll
    for (int off = 32; off > 0; off >>= 1) v += __shfl_down(v, off, 64);
    if ((tid & 63) == 0) wave_sum[tid >> 6] = v;
    __syncthreads();
    if (tid == 0)
        out[0] = (wave_sum[0] + wave_sum[1] + wave_sum[2] + wave_sum[3]) *
                 (1.0f / 4096.0f);
}

extern "C" void kernel_launch(void* const* d_in, const int* in_sizes, int n_in,
                              void* d_out, int out_size, void* d_ws, size_t ws_size,
                              hipStream_t stream) {
    const float* pred = (const float*)d_in[0];
    const float* tgt  = (const float*)d_in[1];
    float* out = (float*)d_out;
    float* partials = (float*)d_ws; // 3136 floats = 12.5 KB, << ws_size

    yolo_main_kernel<<<NBLOCKS, TPB, 0, stream>>>(pred, tgt, partials);
    yolo_reduce_kernel<<<1, TPB, 0, stream>>>(partials, out);
}